// Round 11
// baseline (1080.654 us; speedup 1.0000x reference)
//
#include <hip/hip_runtime.h>
#include <hip/hip_bf16.h>
#include <math.h>

// B=4, M=2048, D=512, H=8. Heads processed in groups of G (adaptive to ws_size; G=4 on this harness).

typedef __attribute__((ext_vector_type(8))) __bf16 bf16x8;
typedef __attribute__((ext_vector_type(4))) __bf16 bf16x4;
typedef __attribute__((ext_vector_type(4))) float f32x4;

#define MFMA16(a, b, c) __builtin_amdgcn_mfma_f32_16x16x32_bf16((a), (b), (c), 0, 0, 0)

__device__ __forceinline__ void g2l16(const void* g, void* l) {
  __builtin_amdgcn_global_load_lds((const __attribute__((address_space(1))) void*)g,
                                   (__attribute__((address_space(3))) void*)l, 16, 0, 0);
}

// ---------------- fused prep: all fp32->bf16 casts + RoPE tables ----------------
__global__ void prep_k(const float* __restrict__ x, const float* __restrict__ wq,
                       const float* __restrict__ wk, const float* __restrict__ wv,
                       const float* __restrict__ wo,
                       __bf16* __restrict__ xb, __bf16* __restrict__ wqb,
                       __bf16* __restrict__ wkb, __bf16* __restrict__ wvb,
                       __bf16* __restrict__ wob,
                       float* __restrict__ ct, float* __restrict__ st) {
  int i = blockIdx.x * 256 + threadIdx.x;
  if (i < 3145728) {  // 3.1M float4 casts: x(1048576) wq/wk/wv/wo(524288 each)
    const float* src;
    __bf16* dst;
    int off = i;
    if (i < 1048576) { src = x; dst = xb; }
    else if (i < 1572864) { src = wq; dst = wqb; off = i - 1048576; }
    else if (i < 2097152) { src = wk; dst = wkb; off = i - 1572864; }
    else if (i < 2621440) { src = wv; dst = wvb; off = i - 2097152; }
    else { src = wo; dst = wob; off = i - 2621440; }
    float4 f = reinterpret_cast<const float4*>(src)[off];
    bf16x4 o;
    o.x = (__bf16)f.x; o.y = (__bf16)f.y; o.z = (__bf16)f.z; o.w = (__bf16)f.w;
    reinterpret_cast<bf16x4*>(dst)[off] = o;
  } else {  // RoPE tables, faithful i-1 quirk
    int idx = i - 3145728;  // 0..524287 = 2048*256
    int m = idx >> 8, j = idx & 255;
    float e = (-2.0f * ((float)j - 1.0f) / 512.0f) * 13.287712379549449f;  // log2(1e4)
    float theta = exp2f(e);
    float ang = (float)m * theta;
    float s, c;
    sincosf(ang, &s, &c);
    ct[idx] = c;
    st[idx] = s;
  }
}

// ---------------- QKV projection: z = which*G + hl; V written directly transposed ----------------
__global__ __launch_bounds__(256, 2) void qkv_gemm_k(
    const __bf16* __restrict__ Xb,
    const __bf16* __restrict__ Wqb, const __bf16* __restrict__ Wkb, const __bf16* __restrict__ Wvb,
    const float* __restrict__ ct, const float* __restrict__ st,
    __bf16* __restrict__ Q, __bf16* __restrict__ K, __bf16* __restrict__ VT,
    int G, int lg, int h0) {
  const int z = blockIdx.z;
  const int which = z >> lg, hl = z & (G - 1);
  const int h = h0 + hl;
  const __bf16* W = (which == 0 ? Wqb : which == 1 ? Wkb : Wvb) + (size_t)h * 262144;

  const int mbase = blockIdx.x * 128;
  const int nbase = blockIdx.y * 128;

  __shared__ alignas(16) __bf16 As[128 * 64];
  __shared__ alignas(16) __bf16 Bs[128 * 64];

  const int tid = threadIdx.x;
  const int lane = tid & 63, wid = tid >> 6;
  const int wr = wid >> 1, wc = wid & 1;
  const int l15 = lane & 15, l4 = lane >> 4;

  f32x4 acc[4][4];
#pragma unroll
  for (int i = 0; i < 4; i++)
#pragma unroll
    for (int j = 0; j < 4; j++) acc[i][j] = f32x4{0.f, 0.f, 0.f, 0.f};

  for (int kt = 0; kt < 8; ++kt) {
    const int kb = kt * 64;
#pragma unroll
    for (int i = 0; i < 4; i++) {
      int chunk = i * 256 + tid;
      int row = chunk >> 3, col = (chunk & 7) * 8;
      g2l16(Xb + (size_t)(mbase + row) * 512 + kb + col, As + (i * 256 + (tid & ~63)) * 8);
    }
#pragma unroll
    for (int i = 0; i < 4; i++) {
      int chunk = i * 256 + tid;
      int row = chunk >> 3, col = (chunk & 7) * 8;
      g2l16(W + (size_t)(nbase + row) * 512 + kb + col, Bs + (i * 256 + (tid & ~63)) * 8);
    }
    __syncthreads();
#pragma unroll
    for (int kk = 0; kk < 2; ++kk) {
      bf16x8 a[4], b[4];
#pragma unroll
      for (int i = 0; i < 4; i++)
        a[i] = *reinterpret_cast<const bf16x8*>(As + (wr * 64 + i * 16 + l15) * 64 + kk * 32 + l4 * 8);
#pragma unroll
      for (int j = 0; j < 4; j++)
        b[j] = *reinterpret_cast<const bf16x8*>(Bs + (wc * 64 + j * 16 + l15) * 64 + kk * 32 + l4 * 8);
#pragma unroll
      for (int i = 0; i < 4; i++)
#pragma unroll
        for (int j = 0; j < 4; j++) acc[i][j] = MFMA16(a[i], b[j], acc[i][j]);
    }
    __syncthreads();
  }

  if (which == 2) {
    // V: write transposed directly into VT[(b*G+hl)][d][m] (8B contiguous bf16x4 stores)
    const int b_ = mbase >> 11;
    const int mloc = mbase & 2047;
    __bf16* Tgw = VT + (size_t)(b_ * G + hl) * 512 * 2048;
#pragma unroll
    for (int i = 0; i < 4; i++) {
#pragma unroll
      for (int j = 0; j < 4; j++) {
        const int col = nbase + wc * 64 + j * 16 + l15;
        const int m0 = mloc + wr * 64 + i * 16 + l4 * 4;
        bf16x4 pk;
        pk.x = (__bf16)acc[i][j][0];
        pk.y = (__bf16)acc[i][j][1];
        pk.z = (__bf16)acc[i][j][2];
        pk.w = (__bf16)acc[i][j][3];
        *reinterpret_cast<bf16x4*>(&Tgw[(size_t)col * 2048 + m0]) = pk;
      }
    }
  } else {
    // Q/K: RoPE + row-major write [(b*G+hl), m, d]
    __bf16* Out = which ? K : Q;
#pragma unroll
    for (int i = 0; i < 4; i++) {
#pragma unroll
      for (int j = 0; j < 4; j++) {
        const int col = nbase + wc * 64 + j * 16 + l15;
#pragma unroll
        for (int r = 0; r < 4; r++) {
          const int rowg = mbase + wr * 64 + i * 16 + l4 * 4 + r;
          const int b_ = rowg >> 11, m = rowg & 2047;
          float v = acc[i][j][r];
          float pv = __shfl_xor(v, 1, 64);  // partner column (col^1) in lane^1
          float c = ct[m * 256 + (col >> 1)];
          float s = st[m * 256 + (col >> 1)];
          v = (col & 1) ? (v * c - pv * s) : (v * c + pv * s);
          Out[(size_t)((b_ * G + hl) * 2048 + m) * 512 + col] = (__bf16)v;
        }
      }
    }
  }
}

// ---------------- causal flash attention v8 ----------------
// QBLK=64, 4 waves (256 thr), KBLK=32, 32*bhN blocks (512 at G=4) -> 2 blocks/CU.
// Mapping: bh = L%bhN (co-resident pair shares bh -> shared K/V stream + same XCD);
// qt = s<16 ? s : 47-s (pair qt+qt'=31 -> 68 tiles per CU, balanced).
// Layouts identical to the proven R10 kernel (XOR-swizzled g2l16 K/V, wave-private Ps).
__global__ __launch_bounds__(256, 2) void flash_attn_k(
    const __bf16* __restrict__ Q, const __bf16* __restrict__ K, const __bf16* __restrict__ VT,
    __bf16* __restrict__ O, int G, int lg) {  // O: [B, M, G*512] bf16
  const int bhN = 4 * G;
  const int L = blockIdx.x;
  const int bh = L % bhN;
  const int s_ = L / bhN;                 // 0..31
  const int qt = (s_ < 16) ? s_ : 47 - s_;
  const int b = bh >> lg, hl = bh & (G - 1);
  const int tid = threadIdx.x, lane = tid & 63, wid = tid >> 6;  // wid 0..3
  const int l15 = lane & 15, l4 = lane >> 4;
  const int qw = qt * 64 + wid * 16;

  __shared__ alignas(16) __bf16 Ks[32 * 512];    // 32KB, 3-bit XOR swizzle on 16B chunks
  __shared__ alignas(16) __bf16 Vts[512 * 32];   // 32KB, 2-bit XOR swizzle
  __shared__ alignas(16) __bf16 Ps[4][16 * 32];  // 4KB, wave-private P

  const __bf16* Qg = Q + ((size_t)bh * 2048 + qw) * 512;
  const __bf16* Kg = K + (size_t)bh * 2048 * 512;
  const __bf16* Tg = VT + (size_t)bh * 512 * 2048;

  bf16x8 qf[16];
#pragma unroll
  for (int c = 0; c < 16; c++)
    qf[c] = *reinterpret_cast<const bf16x8*>(Qg + l15 * 512 + c * 32 + l4 * 8);

  f32x4 acc[32];
#pragma unroll
  for (int n = 0; n < 32; n++) acc[n] = f32x4{0.f, 0.f, 0.f, 0.f};
  float mrow[4] = {-INFINITY, -INFINITY, -INFINITY, -INFINITY};
  float lrow[4] = {0.f, 0.f, 0.f, 0.f};

  const float scale = 0.04419417382415922f;  // 1/sqrt(512)
  const int ntiles = 2 * qt + 2;

  for (int kt = 0; kt < ntiles; ++kt) {
    const int kb = kt * 32;
#pragma unroll
    for (int i = 0; i < 8; i++) {
      int chunk = i * 256 + tid;
      int row = chunk >> 6, c16 = chunk & 63;
      g2l16(Kg + (size_t)(kb + row) * 512 + ((c16 ^ (row & 7)) << 3),
            Ks + (i * 256 + (tid & ~63)) * 8);
    }
#pragma unroll
    for (int i = 0; i < 8; i++) {
      int chunk = i * 256 + tid;
      int row = chunk >> 2, c4 = chunk & 3;
      g2l16(Tg + (size_t)row * 2048 + kb + ((c4 ^ (row & 3)) << 3),
            Vts + (i * 256 + (tid & ~63)) * 8);
    }
    __syncthreads();

    f32x4 sv0 = f32x4{0.f, 0.f, 0.f, 0.f}, sv1 = f32x4{0.f, 0.f, 0.f, 0.f};
#pragma unroll
    for (int c = 0; c < 16; c++) {
      const int off = c * 32 + l4 * 8;
      const int r0 = l15, r1 = 16 + l15;
      bf16x8 b0 = *reinterpret_cast<const bf16x8*>(Ks + r0 * 512 + (off ^ ((r0 & 7) << 3)));
      bf16x8 b1 = *reinterpret_cast<const bf16x8*>(Ks + r1 * 512 + (off ^ ((r1 & 7) << 3)));
      sv0 = MFMA16(qf[c], b0, sv0);
      sv1 = MFMA16(qf[c], b1, sv1);
    }

    float alpha[4];
#pragma unroll
    for (int r = 0; r < 4; r++) {
      const int qg = qw + l4 * 4 + r;
      float s0 = sv0[r] * scale;
      float s1 = sv1[r] * scale;
      if (kb + l15 > qg) s0 = -INFINITY;
      if (kb + 16 + l15 > qg) s1 = -INFINITY;
      float mx = fmaxf(s0, s1);
      mx = fmaxf(mx, __shfl_xor(mx, 1, 64));
      mx = fmaxf(mx, __shfl_xor(mx, 2, 64));
      mx = fmaxf(mx, __shfl_xor(mx, 4, 64));
      mx = fmaxf(mx, __shfl_xor(mx, 8, 64));
      const float mn = fmaxf(mrow[r], mx);
      const float p0 = __expf(s0 - mn);
      const float p1 = __expf(s1 - mn);
      const float a_ = __expf(mrow[r] - mn);
      float rs = p0 + p1;
      rs += __shfl_xor(rs, 1, 64);
      rs += __shfl_xor(rs, 2, 64);
      rs += __shfl_xor(rs, 4, 64);
      rs += __shfl_xor(rs, 8, 64);
      lrow[r] = lrow[r] * a_ + rs;
      mrow[r] = mn;
      alpha[r] = a_;
      __bf16* P = &Ps[wid][0];
      P[(l4 * 4 + r) * 32 + l15] = (__bf16)p0;
      P[(l4 * 4 + r) * 32 + 16 + l15] = (__bf16)p1;
    }
#pragma unroll
    for (int n = 0; n < 32; n++) {
#pragma unroll
      for (int r = 0; r < 4; r++) acc[n][r] *= alpha[r];
    }
    bf16x8 pf = *reinterpret_cast<const bf16x8*>(&Ps[wid][0] + l15 * 32 + l4 * 8);
#pragma unroll
    for (int n = 0; n < 32; n++) {
      const int row = n * 16 + l15;
      bf16x8 vb = *reinterpret_cast<const bf16x8*>(Vts + row * 32 + ((l4 * 8) ^ ((row & 3) << 3)));
      acc[n] = MFMA16(pf, vb, acc[n]);
    }
    __syncthreads();
  }

#pragma unroll
  for (int r = 0; r < 4; r++) {
    const int qg = qw + l4 * 4 + r;
    const float inv = 1.0f / lrow[r];
    __bf16* Og = O + ((size_t)(b * 2048 + qg) * (512 * G) + hl * 512);
#pragma unroll
    for (int n = 0; n < 32; n++) Og[n * 16 + l15] = (__bf16)(acc[n][r] * inv);
  }
}

// ---------------- output projection: 128x64 tile, grid (64,8) -> 2 blocks/CU TLP ----------------
// NOTE: wob row stride is ALWAYS 4096 ([512][H*D]); A (O) row stride is 512*G.
__global__ __launch_bounds__(256) void out_gemm_k(
    const __bf16* __restrict__ A, const __bf16* __restrict__ Wo,
    const float* __restrict__ bias, float* __restrict__ Y, int G, int first) {
  const int AS = 512 * G;
  const int mbase = blockIdx.x * 128, nbase = blockIdx.y * 64;
  __shared__ alignas(16) __bf16 As[128 * 64];  // 16KB
  __shared__ alignas(16) __bf16 Bs[64 * 64];   // 8KB
  const int tid = threadIdx.x;
  const int lane = tid & 63, wid = tid >> 6;
  const int wr = wid >> 1, wc = wid & 1;
  const int l15 = lane & 15, l4 = lane >> 4;

  f32x4 acc[4][2];
#pragma unroll
  for (int i = 0; i < 4; i++)
#pragma unroll
    for (int j = 0; j < 2; j++) acc[i][j] = f32x4{0.f, 0.f, 0.f, 0.f};

  const int nkt = 8 * G;
  for (int kt = 0; kt < nkt; ++kt) {
    const int kb = kt * 64;
#pragma unroll
    for (int i = 0; i < 4; i++) {
      int chunk = i * 256 + tid;
      int row = chunk >> 3, col = (chunk & 7) * 8;
      g2l16(A + (size_t)(mbase + row) * AS + kb + col, As + (i * 256 + (tid & ~63)) * 8);
    }
#pragma unroll
    for (int i = 0; i < 2; i++) {
      int chunk = i * 256 + tid;
      int row = chunk >> 3, col = (chunk & 7) * 8;
      g2l16(Wo + (size_t)(nbase + row) * 4096 + kb + col, Bs + (i * 256 + (tid & ~63)) * 8);
    }
    __syncthreads();
#pragma unroll
    for (int kk = 0; kk < 2; ++kk) {
      bf16x8 a[4], b[2];
#pragma unroll
      for (int i = 0; i < 4; i++)
        a[i] = *reinterpret_cast<const bf16x8*>(As + (wr * 64 + i * 16 + l15) * 64 + kk * 32 + l4 * 8);
#pragma unroll
      for (int j = 0; j < 2; j++)
        b[j] = *reinterpret_cast<const bf16x8*>(Bs + (wc * 32 + j * 16 + l15) * 64 + kk * 32 + l4 * 8);
#pragma unroll
      for (int i = 0; i < 4; i++)
#pragma unroll
        for (int j = 0; j < 2; j++) acc[i][j] = MFMA16(a[i], b[j], acc[i][j]);
    }
    __syncthreads();
  }

#pragma unroll
  for (int i = 0; i < 4; i++) {
#pragma unroll
    for (int j = 0; j < 2; j++) {
      const int col = nbase + wc * 32 + j * 16 + l15;
#pragma unroll
      for (int r = 0; r < 4; r++) {
        const int row = mbase + wr * 64 + i * 16 + l4 * 4 + r;
        float prev = first ? bias[col] : Y[(size_t)row * 512 + col];
        Y[(size_t)row * 512 + col] = prev + acc[i][j][r];
      }
    }
  }
}

extern "C" void kernel_launch(void* const* d_in, const int* in_sizes, int n_in,
                              void* d_out, int out_size, void* d_ws, size_t ws_size,
                              hipStream_t stream) {
  (void)in_sizes; (void)n_in; (void)out_size;
  const float* x = (const float*)d_in[0];
  const float* wq = (const float*)d_in[1];
  const float* wk = (const float*)d_in[2];
  const float* wv = (const float*)d_in[3];
  const float* wo = (const float*)d_in[4];
  const float* bo = (const float*)d_in[5];
  float* y = (float*)d_out;

  char* base = (char*)d_ws;
  size_t off = 0;
  auto alloc = [&](size_t bytes) -> void* {
    void* p = base + off;
    off += (bytes + 255) & ~(size_t)255;
    return p;
  };
  __bf16* xb = (__bf16*)alloc((size_t)8192 * 512 * 2);
  __bf16* wqb = (__bf16*)alloc((size_t)8 * 512 * 512 * 2);
  __bf16* wkb = (__bf16*)alloc((size_t)8 * 512 * 512 * 2);
  __bf16* wvb = (__bf16*)alloc((size_t)8 * 512 * 512 * 2);
  __bf16* wob = (__bf16*)alloc((size_t)512 * 4096 * 2);
  float* ct = (float*)alloc((size_t)2048 * 256 * 4);
  float* st = (float*)alloc((size_t)2048 * 256 * 4);
  const size_t persist = off;

  // choose largest head-group G with persist + 4 * (G*4*2048*512*2) <= ws_size
  int G = 0, lg = 0;
  for (int g = 8, l = 3; g >= 1; g >>= 1, --l) {
    size_t T = ((size_t)g * 4 * 2048 * 512 * 2 + 255) & ~(size_t)255;
    if (persist + 4 * T <= ws_size) { G = g; lg = l; break; }
  }
  if (G == 0) return;

  size_t T = ((size_t)G * 4 * 2048 * 512 * 2 + 255) & ~(size_t)255;
  __bf16* Qb = (__bf16*)(base + persist);
  __bf16* Kb = (__bf16*)(base + persist + T);
  __bf16* VTb = (__bf16*)(base + persist + 2 * T);
  __bf16* Ob = (__bf16*)(base + persist + 3 * T);

  prep_k<<<14336, 256, 0, stream>>>(x, wq, wk, wv, wo, xb, wqb, wkb, wvb, wob, ct, st);

  for (int h0 = 0; h0 < 8; h0 += G) {
    qkv_gemm_k<<<dim3(64, 4, 3 * G), 256, 0, stream>>>(xb, wqb, wkb, wvb, ct, st,
                                                       Qb, Kb, VTb, G, lg, h0);
    flash_attn_k<<<dim3(32 * 4 * G), 256, 0, stream>>>(Qb, Kb, VTb, Ob, G, lg);
    out_gemm_k<<<dim3(64, 8), 256, 0, stream>>>(Ob, wob + h0 * 512, bo, y, G, h0 == 0);
  }
}